// Round 6
// baseline (261.317 us; speedup 1.0000x reference)
//
#include <hip/hip_runtime.h>
#include <hip/hip_bf16.h>

// Problem: MultiHeadAttention  B=2,S=2048,E=1024,H=16,D=64
// R10: attn only (GEMMs/prep = R9, isolation):
//   - K/V LDS staging REMOVED. Per-tile LDS accounting showed ~2100 cyc/tile
//     of LDS pipe (8x broadcast-redundant Kf/Vf reads + staging) ~= 30us of a
//     42us kernel. K/V per bh = 512KB; each XCD sees 4 bh (blockIdx mapping)
//     = 2MB -> L2-resident. Read K/V fragments straight from L2 (16rows x 64B
//     per instr, 16B-aligned). m169 precedent: drop staging when cache-fits.
//   - No barriers in main loop; waves free-run to their causal bound.
//   - v_cvt_pk_bf16_f32 asm replaces bit-twiddle pk2bf (T12 primitive).
//   LDS = P exchange + O epilogue only (18.4KB). __launch_bounds__(512,4).

typedef __attribute__((ext_vector_type(4))) float  f32x4;
typedef __attribute__((ext_vector_type(8))) short  bf16x8;

#define S_LEN 2048
#define EMB   1024
#define NH    16
#define HD    64

#define LDSW 72   // 64 + 8 pad: 144B row stride -- KEEP multiple of 8 shorts
                  // (16B) or every ds_*_b128 goes through the misaligned slow
                  // path (R8: 3x slowdown, zero reported conflicts).

// q pre-scale folds 1/sqrt(64) and log2(e):  0.125 * 1.4426950408889634
#define QSCALE 0.18033688011112042f

#if __has_builtin(__builtin_amdgcn_exp2f)
#define EXP2(x) __builtin_amdgcn_exp2f(x)
#else
#define EXP2(x) __exp2f(x)
#endif

__device__ __forceinline__ unsigned short f2bf(float f) {
    __hip_bfloat16 h = __float2bfloat16(f);
    return __builtin_bit_cast(unsigned short, h);
}
// RNE-pack two non-NaN floats to packed bf16x2 (bit-twiddle; used off hot path)
__device__ __forceinline__ unsigned int pk2bf(float a, float b) {
    unsigned int x = __builtin_bit_cast(unsigned int, a);
    unsigned int y = __builtin_bit_cast(unsigned int, b);
    x += 0x7FFFu + ((x >> 16) & 1u);
    y += 0x7FFFu + ((y >> 16) & 1u);
    return (x >> 16) | (y & 0xFFFF0000u);
}
// HW packed cvt (RNE), gfx950: no builtin, asm only
__device__ __forceinline__ unsigned int cvtpk(float lo, float hi) {
    unsigned int r;
    asm("v_cvt_pk_bf16_f32 %0, %1, %2" : "=v"(r) : "v"(lo), "v"(hi));
    return r;
}

// ---------------- fused prep: casts + wcat build ----------------
// blocks [0,4096)        : cast x        (4096*1024 floats)
// blocks [4096,5120)     : cast w_proj   (1024*1024 floats)
// blocks [5120,5504)     : build wcat^T
__global__ __launch_bounds__(256) void prep(const float* __restrict__ x,
                                            const float* __restrict__ wq,
                                            const float* __restrict__ wk,
                                            const float* __restrict__ wv,
                                            const float* __restrict__ wproj,
                                            unsigned short* __restrict__ xb,
                                            unsigned short* __restrict__ wpb,
                                            unsigned short* __restrict__ wcat) {
    int blk = blockIdx.x;
    if (blk < 5120) {
        const float* in = (blk < 4096) ? x : wproj;
        unsigned short* out = (blk < 4096) ? xb : wpb;
        int bb = (blk < 4096) ? blk : blk - 4096;
        int i = (bb * 256 + threadIdx.x) * 4;
        float4 v = *(const float4*)(in + i);
        out[i + 0] = f2bf(v.x);
        out[i + 1] = f2bf(v.y);
        out[i + 2] = f2bf(v.z);
        out[i + 3] = f2bf(v.w);
    } else {
        int b2  = blk - 5120;
        int et  = b2 & 7;
        int h   = (b2 >> 3) & 15;
        int qkv = b2 >> 7;
        const float* w = (qkv == 0) ? wq : (qkv == 1) ? wk : wv;
        int t = threadIdx.x;
        int d = t & 63, es = t >> 6;
        int e0 = et * 128 + es * 32;

        unsigned short val[32];
        #pragma unroll
        for (int i = 0; i < 32; i++)
            val[i] = f2bf(w[(size_t)h * 65536 + (size_t)(e0 + i) * 64 + d]);

        size_t n = (size_t)qkv * 1024 + h * 64 + d;
        #pragma unroll
        for (int k = 0; k < 4; k++)
            *(uint4*)(wcat + n * 1024 + e0 + k * 8) = *(const uint4*)(val + k * 8);
    }
}

// ---------------- GEMM core: C[128x128] = A[M,K] * Bt[N,K]^T, bf16, fp32 acc ----
// Padded [128][72] LDS, stage within phase, 2 barriers per K-step.
// 3 blocks/CU TLP hides the staging round-trip.
__device__ __forceinline__ void gemm_tile_core(const unsigned short* __restrict__ A,
                                               const unsigned short* __restrict__ Bt,
                                               int K, int m0, int n0,
                                               unsigned short* As, unsigned short* Bs,
                                               f32x4 acc[4][4]) {
    const int t    = threadIdx.x;
    const int wave = t >> 6, lane = t & 63;
    const int wm   = (wave >> 1) * 64, wn = (wave & 1) * 64;
    const int lr   = lane & 15, quad = lane >> 4;
    const int sr   = t >> 3;             // 0..31
    const int sc   = (t & 7) * 8;        // bf16 col

    #pragma unroll
    for (int i = 0; i < 4; i++)
        #pragma unroll
        for (int j = 0; j < 4; j++) acc[i][j] = (f32x4)(0.0f);

    for (int k0 = 0; k0 < K; k0 += 64) {
        __syncthreads();
        #pragma unroll
        for (int p = 0; p < 4; ++p) {
            int r = p * 32 + sr;
            uint4 av = *(const uint4*)(A  + (size_t)(m0 + r) * K + k0 + sc);
            uint4 bv = *(const uint4*)(Bt + (size_t)(n0 + r) * K + k0 + sc);
            *(uint4*)(As + r * LDSW + sc) = av;
            *(uint4*)(Bs + r * LDSW + sc) = bv;
        }
        __syncthreads();
        #pragma unroll
        for (int kk = 0; kk < 64; kk += 32) {
            bf16x8 af[4], bfr[4];
            #pragma unroll
            for (int i = 0; i < 4; i++)
                af[i] = *(const bf16x8*)(As + (wm + i * 16 + lr) * LDSW + kk + quad * 8);
            #pragma unroll
            for (int j = 0; j < 4; j++)
                bfr[j] = *(const bf16x8*)(Bs + (wn + j * 16 + lr) * LDSW + kk + quad * 8);
            #pragma unroll
            for (int i = 0; i < 4; i++)
                #pragma unroll
                for (int j = 0; j < 4; j++)
                    acc[i][j] = __builtin_amdgcn_mfma_f32_16x16x32_bf16(af[i], bfr[j], acc[i][j], 0, 0, 0);
        }
    }
}

// GEMM1: QKV = x * Wcat.
//   Q (scaled) -> qb[bh][s][d], K -> kb[bh][s][d]  (both via LDS roundtrip, b128 out)
//   V -> LDS-transpose -> vt[bh][d][s] (b128 out)
__global__ __launch_bounds__(256) void gemm_qkv(const unsigned short* __restrict__ xb,
                                                const unsigned short* __restrict__ wcat,
                                                unsigned short* __restrict__ qb,
                                                unsigned short* __restrict__ kb,
                                                unsigned short* __restrict__ vt) {
    __shared__ unsigned short Smem[2 * 128 * LDSW];   // 36864B; Tb needs 34816B
    unsigned short* As = Smem;
    unsigned short* Bs = Smem + 128 * LDSW;
    f32x4 acc[4][4];
    int m0 = blockIdx.x * 128, n0 = blockIdx.y * 128;
    gemm_tile_core(xb, wcat, EMB, m0, n0, As, Bs, acc);

    int t = threadIdx.x, wave = t >> 6, lane = t & 63;
    int wm = (wave >> 1) * 64, wn = (wave & 1) * 64, lr = lane & 15, quad = lane >> 4;
    int b  = m0 >> 11;
    int s0 = m0 & 2047;
    unsigned short* Tb = Smem;                 // reuse: [128][136]

    if (n0 < 2048) {
        bool isQ = (n0 < 1024);
        unsigned short* dst = isQ ? qb : kb;
        float sc = isQ ? QSCALE : 1.0f;
        __syncthreads();                       // done reading As/Bs
        #pragma unroll
        for (int i = 0; i < 4; i++)
            #pragma unroll
            for (int j = 0; j < 4; j++)
                #pragma unroll
                for (int e = 0; e < 4; e++)
                    Tb[(wm + i * 16 + quad * 4 + e) * 136 + wn + j * 16 + lr] = f2bf(acc[i][j][e] * sc);
        __syncthreads();
        #pragma unroll
        for (int p = 0; p < 8; p++) {
            int r  = p * 16 + (t >> 4);
            int ch = (t & 15) * 8;
            int n  = n0 + ch;
            int h  = (n >> 6) & 15, d = ch & 63;
            *(uint4*)(dst + (((size_t)(b * NH + h)) * S_LEN + s0 + r) * HD + d) =
                *(const uint4*)(Tb + r * 136 + ch);
        }
    } else {
        // V: transpose in LDS, then coalesced rows of vt[bh][d][s]
        __syncthreads();
        #pragma unroll
        for (int i = 0; i < 4; i++)
            #pragma unroll
            for (int j = 0; j < 4; j++)
                #pragma unroll
                for (int e = 0; e < 4; e++)
                    Tb[(wn + j * 16 + lr) * 136 + (wm + i * 16 + quad * 4 + e)] = f2bf(acc[i][j][e]);
        __syncthreads();
        #pragma unroll
        for (int p = 0; p < 8; p++) {
            int nl  = p * 16 + (t >> 4);
            int n   = n0 + nl;
            int h   = (n >> 6) & 15, d = n & 63;
            int col = (t & 15) * 8;
            *(uint4*)(vt + (((size_t)(b * NH + h)) * HD + d) * S_LEN + s0 + col) =
                *(const uint4*)(Tb + nl * 136 + col);
        }
    }
}

// GEMM2: out = ao * w_proj^T + b
__global__ __launch_bounds__(256) void gemm_proj(const unsigned short* __restrict__ ao,
                                                 const unsigned short* __restrict__ wpb,
                                                 const float* __restrict__ bproj,
                                                 float* __restrict__ out) {
    __shared__ unsigned short Smem[2 * 128 * LDSW];
    f32x4 acc[4][4];
    int m0 = blockIdx.x * 128, n0 = blockIdx.y * 128;
    gemm_tile_core(ao, wpb, EMB, m0, n0, Smem, Smem + 128 * LDSW, acc);

    int t = threadIdx.x, wave = t >> 6, lane = t & 63;
    int wm = (wave >> 1) * 64, wn = (wave & 1) * 64, lr = lane & 15, quad = lane >> 4;
    #pragma unroll
    for (int i = 0; i < 4; i++)
        #pragma unroll
        for (int j = 0; j < 4; j++) {
            int n = n0 + wn + j * 16 + lr;
            float bias = bproj[n];
            #pragma unroll
            for (int e = 0; e < 4; e++) {
                int m = m0 + wm + i * 16 + quad * 4 + e;
                out[(size_t)m * EMB + n] = acc[i][j][e] + bias;
            }
        }
}

// ---------------- MFMA flash attention, causal, S^T-swapped, L2-direct ----------------
// 512 blocks x 512 threads = 32 bh x 16 chunks of 128 rows; 8 waves x 16 rows.
// NO K/V LDS staging: fragments read straight from global (L2-resident:
// blockIdx mapping gives each XCD 4 bh = 2MB KV working set < 4MB L2).
// NO main-loop barriers: each wave free-runs to its causal tile bound.
// LDS only for the wave-private P exchange (write P^T cols, read A-frag rows)
// and the O epilogue. l via MFMA-vs-ones. exp2 unbiased (factor cancels).
__global__ __launch_bounds__(512, 4) void attn_mfma(const unsigned short* __restrict__ qb,
                                                    const unsigned short* __restrict__ kb,
                                                    const unsigned short* __restrict__ vtb,
                                                    unsigned short* __restrict__ ao) {
    __shared__ unsigned short Ps[128 * LDSW];       // 8 waves x 16 rows [q][key]; reused as O buffer

    int bIdx = blockIdx.x;
    int bh   = bIdx & 31;
    int grp  = bIdx >> 5;
    int chunk = (grp < 8) ? (15 - grp) : (grp - 8);   // heavy chunks first
    int b = bh >> 4, h = bh & 15;
    int t = threadIdx.x, wave = t >> 6, lane = t & 63;
    int c = lane & 15, quad = lane >> 4;

    const unsigned short* Q  = qb  + (size_t)bh * S_LEN * HD;
    const unsigned short* K  = kb  + (size_t)bh * S_LEN * HD;
    const unsigned short* Vt = vtb + (size_t)bh * HD * S_LEN;

    int r0 = chunk * 128;
    int rw = r0 + wave * 16;                 // wave's 16 q rows

    // Q frags (B-operand): B[n=q=c][k=d]
    bf16x8 Qf[2];
    #pragma unroll
    for (int ks = 0; ks < 2; ks++)
        Qf[ks] = *(const bf16x8*)(Q + (size_t)(rw + c) * HD + ks * 32 + quad * 8);

    f32x4 O[4];
    f32x4 lacc = (f32x4)(0.0f);
    #pragma unroll
    for (int dt = 0; dt < 4; dt++) O[dt] = (f32x4)(0.0f);

    const short oneb = (short)0x3F80;
    bf16x8 ones = {oneb, oneb, oneb, oneb, oneb, oneb, oneb, oneb};

    unsigned short* Pw = Ps + wave * 16 * LDSW;

    // per-lane fragment base addresses
    const unsigned short* Kfb = K  + (size_t)c * HD + quad * 8;          // + key*HD + ks*32
    const unsigned short* Vfb = Vt + (size_t)c * S_LEN + quad * 8;       // + (dt*16)*S_LEN + j0 + ks*32

    int ntw = ((rw + 15) >> 6) + 1;          // causal tile bound for this wave

    for (int tt = 0; tt < ntw; ++tt) {
        int j0 = tt << 6;

        // S^T = K Q^T : D[m=key][n=q], K-frags straight from L2
        f32x4 S4[4];
        #pragma unroll
        for (int kt = 0; kt < 4; kt++) S4[kt] = (f32x4)(0.0f);
        __builtin_amdgcn_s_setprio(1);
        #pragma unroll
        for (int ks = 0; ks < 2; ks++) {
            bf16x8 Kf[4];
            #pragma unroll
            for (int kt = 0; kt < 4; kt++)
                Kf[kt] = *(const bf16x8*)(Kfb + (size_t)(j0 + kt * 16) * HD + ks * 32);
            #pragma unroll
            for (int kt = 0; kt < 4; kt++)
                S4[kt] = __builtin_amdgcn_mfma_f32_16x16x32_bf16(Kf[kt], Qf[ks], S4[kt], 0, 0, 0);
        }
        __builtin_amdgcn_s_setprio(0);

        bool need_mask = (j0 + 63 > rw);
        #pragma unroll
        for (int kt = 0; kt < 4; kt++) {
            float p0 = EXP2(S4[kt][0]);
            float p1 = EXP2(S4[kt][1]);
            float p2 = EXP2(S4[kt][2]);
            float p3 = EXP2(S4[kt][3]);
            if (need_mask) {
                int key  = j0 + kt * 16 + quad * 4;
                int qrow = rw + c;
                if (key + 0 > qrow) p0 = 0.0f;
                if (key + 1 > qrow) p1 = 0.0f;
                if (key + 2 > qrow) p2 = 0.0f;
                if (key + 3 > qrow) p3 = 0.0f;
            }
            uint2 pk;
            pk.x = cvtpk(p0, p1);
            pk.y = cvtpk(p2, p3);
            *(uint2*)(Pw + c * LDSW + kt * 16 + quad * 4) = pk;
        }

        // O += P V ; l += P * ones  (A from Pw[q][key], V-frags straight from L2)
        __builtin_amdgcn_s_setprio(1);
        #pragma unroll
        for (int ks = 0; ks < 2; ks++) {
            bf16x8 Af = *(const bf16x8*)(Pw + c * LDSW + ks * 32 + quad * 8);
            lacc = __builtin_amdgcn_mfma_f32_16x16x32_bf16(Af, ones, lacc, 0, 0, 0);
            #pragma unroll
            for (int dt = 0; dt < 4; dt++) {
                bf16x8 Vf = *(const bf16x8*)(Vfb + (size_t)(dt * 16) * S_LEN + j0 + ks * 32);
                O[dt] = __builtin_amdgcn_mfma_f32_16x16x32_bf16(Af, Vf, O[dt], 0, 0, 0);
            }
        }
        __builtin_amdgcn_s_setprio(0);
    }

    // normalize: l lands in C-layout rows (quad*4+e) == O's rows; no cross-lane needed
    float inv[4];
    #pragma unroll
    for (int e = 0; e < 4; e++) inv[e] = 1.0f / lacc[e];

    // O -> wave-private LDS region (aliases Pw) -> coalesced b128 global
    int sr = t >> 3, scg = (t & 7) * 8;      // 512 thr: sr 0..63
    #pragma unroll
    for (int dt = 0; dt < 4; dt++)
        #pragma unroll
        for (int e = 0; e < 4; e++)
            Ps[(wave * 16 + quad * 4 + e) * LDSW + dt * 16 + c] = f2bf(O[dt][e] * inv[e]);
    __syncthreads();
    #pragma unroll
    for (int p = 0; p < 2; p++) {
        int r = p * 64 + sr;
        *(uint4*)(ao + ((size_t)(b * S_LEN + r0 + r)) * EMB + h * HD + scg) =
            *(const uint4*)(Ps + r * LDSW + scg);
    }
}

// ---------------- launch ----------------
extern "C" void kernel_launch(void* const* d_in, const int* in_sizes, int n_in,
                              void* d_out, int out_size, void* d_ws, size_t ws_size,
                              hipStream_t stream) {
    const float* x     = (const float*)d_in[0];
    const float* wq    = (const float*)d_in[1];
    const float* wk    = (const float*)d_in[2];
    const float* wv    = (const float*)d_in[3];
    const float* wproj = (const float*)d_in[4];
    const float* bproj = (const float*)d_in[5];
    float* out = (float*)d_out;

    char* ws = (char*)d_ws;
    unsigned short* xb   = (unsigned short*)(ws + 0);          //  8 MB  [4096,1024]
    unsigned short* wcat = (unsigned short*)(ws + 8388608);    //  6 MB  [3072,1024] (B^T)
    unsigned short* wpb  = (unsigned short*)(ws + 14680064);   //  2 MB  [1024,1024] (B^T)
    unsigned short* qb   = (unsigned short*)(ws + 16777216);   //  8 MB  [B,H,S,D] (x QSCALE)
    unsigned short* kb   = (unsigned short*)(ws + 25165824);   //  8 MB  [B,H,S,D]
    unsigned short* vt   = (unsigned short*)(ws + 33554432);   //  8 MB  [B,H,D,S]
    unsigned short* ao   = (unsigned short*)(ws + 41943040);   //  8 MB  [4096,1024]

    prep<<<5504, 256, 0, stream>>>(x, wq, wk, wv, wproj, xb, wpb, wcat);
    gemm_qkv<<<dim3(32, 24), 256, 0, stream>>>(xb, wcat, qb, kb, vt);
    attn_mfma<<<512, 512, 0, stream>>>(qb, kb, vt, ao);
    gemm_proj<<<dim3(32, 8), 256, 0, stream>>>(ao, wpb, bproj, out);
}

// Round 7
// 190.788 us; speedup vs baseline: 1.3697x; 1.3697x over previous
//
#include <hip/hip_runtime.h>
#include <hip/hip_bf16.h>

// Problem: MultiHeadAttention  B=2,S=2048,E=1024,H=16,D=64
// R11: (a) attn: revert R10's L2-direct reads (gather-split transactions ->
//     latency-bound, 3x slower). Back to R9 LDS-staged dbuf structure, BUT
//     each wave now owns 32 q-rows (2x16 groups): one Kf/Vf LDS read feeds
//     two MFMAs -> K/V fragment-read traffic per q-row halves. 512 blocks x
//     256 thr (4 waves), same chunk pairing / one barrier per tile.
//     (b) x-cast folded into gemm_qkv A-staging, wproj-cast into gemm_proj
//     B-staging (float4x2 load + v_cvt_pk_bf16_f32). prep = wcat only.

typedef __attribute__((ext_vector_type(4))) float  f32x4;
typedef __attribute__((ext_vector_type(8))) short  bf16x8;

#define S_LEN 2048
#define EMB   1024
#define NH    16
#define HD    64

#define LDSW 72   // 64 + 8 pad: 144B row stride -- KEEP multiple of 8 shorts
                  // (16B) or every ds_*_b128 goes through the misaligned slow
                  // path (R8: 3x slowdown, zero reported conflicts).

// q pre-scale folds 1/sqrt(64) and log2(e):  0.125 * 1.4426950408889634
#define QSCALE 0.18033688011112042f

#if __has_builtin(__builtin_amdgcn_exp2f)
#define EXP2(x) __builtin_amdgcn_exp2f(x)
#else
#define EXP2(x) __exp2f(x)
#endif

__device__ __forceinline__ unsigned short f2bf(float f) {
    __hip_bfloat16 h = __float2bfloat16(f);
    return __builtin_bit_cast(unsigned short, h);
}
// HW packed cvt f32x2 -> bf16x2 (RNE), gfx950: no builtin, asm only.
// D[15:0]=bf16(lo), D[31:16]=bf16(hi)  => memory order lo,hi.
__device__ __forceinline__ unsigned int cvtpk(float lo, float hi) {
    unsigned int r;
    asm("v_cvt_pk_bf16_f32 %0, %1, %2" : "=v"(r) : "v"(lo), "v"(hi));
    return r;
}

// ---------------- prep: wcat build only ----------------
// wcat[n][e] (n = qkv*1024 + h*64 + d)  <-  w{q,k,v}[h][e][d]
__global__ __launch_bounds__(256) void prep_wcat(const float* __restrict__ wq,
                                                 const float* __restrict__ wk,
                                                 const float* __restrict__ wv,
                                                 unsigned short* __restrict__ wcat) {
    int blk = blockIdx.x;
    int et  = blk & 7;
    int h   = (blk >> 3) & 15;
    int qkv = blk >> 7;
    const float* w = (qkv == 0) ? wq : (qkv == 1) ? wk : wv;
    int t = threadIdx.x;
    int d = t & 63, es = t >> 6;
    int e0 = et * 128 + es * 32;

    unsigned short val[32];
    #pragma unroll
    for (int i = 0; i < 32; i++)
        val[i] = f2bf(w[(size_t)h * 65536 + (size_t)(e0 + i) * 64 + d]);

    size_t n = (size_t)qkv * 1024 + h * 64 + d;
    #pragma unroll
    for (int k = 0; k < 4; k++)
        *(uint4*)(wcat + n * 1024 + e0 + k * 8) = *(const uint4*)(val + k * 8);
}

// ---------------- GEMM core: C[128x128] = A[M,K] * Bt[N,K]^T, fp32 acc ----
// Padded [128][72] LDS, stage within phase, 2 barriers per K-step.
// AF32/BF32: operand is row-major f32; staged with inline cvt_pk to bf16.
template<int AF32, int BF32>
__device__ __forceinline__ void gemm_tile_core(const void* __restrict__ Av,
                                               const void* __restrict__ Btv,
                                               int K, int m0, int n0,
                                               unsigned short* As, unsigned short* Bs,
                                               f32x4 acc[4][4]) {
    const int t    = threadIdx.x;
    const int wave = t >> 6, lane = t & 63;
    const int wm   = (wave >> 1) * 64, wn = (wave & 1) * 64;
    const int lr   = lane & 15, quad = lane >> 4;
    const int sr   = t >> 3;             // 0..31
    const int sc   = (t & 7) * 8;        // col (elements)

    #pragma unroll
    for (int i = 0; i < 4; i++)
        #pragma unroll
        for (int j = 0; j < 4; j++) acc[i][j] = (f32x4)(0.0f);

    for (int k0 = 0; k0 < K; k0 += 64) {
        __syncthreads();
        #pragma unroll
        for (int p = 0; p < 4; ++p) {
            int r = p * 32 + sr;
            uint4 av, bv;
            if (AF32) {
                const float* Af = (const float*)Av + (size_t)(m0 + r) * K + k0 + sc;
                float4 v0 = *(const float4*)Af;
                float4 v1 = *(const float4*)(Af + 4);
                av.x = cvtpk(v0.x, v0.y); av.y = cvtpk(v0.z, v0.w);
                av.z = cvtpk(v1.x, v1.y); av.w = cvtpk(v1.z, v1.w);
            } else {
                av = *(const uint4*)((const unsigned short*)Av + (size_t)(m0 + r) * K + k0 + sc);
            }
            if (BF32) {
                const float* Bf = (const float*)Btv + (size_t)(n0 + r) * K + k0 + sc;
                float4 v0 = *(const float4*)Bf;
                float4 v1 = *(const float4*)(Bf + 4);
                bv.x = cvtpk(v0.x, v0.y); bv.y = cvtpk(v0.z, v0.w);
                bv.z = cvtpk(v1.x, v1.y); bv.w = cvtpk(v1.z, v1.w);
            } else {
                bv = *(const uint4*)((const unsigned short*)Btv + (size_t)(n0 + r) * K + k0 + sc);
            }
            *(uint4*)(As + r * LDSW + sc) = av;
            *(uint4*)(Bs + r * LDSW + sc) = bv;
        }
        __syncthreads();
        #pragma unroll
        for (int kk = 0; kk < 64; kk += 32) {
            bf16x8 af[4], bfr[4];
            #pragma unroll
            for (int i = 0; i < 4; i++)
                af[i] = *(const bf16x8*)(As + (wm + i * 16 + lr) * LDSW + kk + quad * 8);
            #pragma unroll
            for (int j = 0; j < 4; j++)
                bfr[j] = *(const bf16x8*)(Bs + (wn + j * 16 + lr) * LDSW + kk + quad * 8);
            #pragma unroll
            for (int i = 0; i < 4; i++)
                #pragma unroll
                for (int j = 0; j < 4; j++)
                    acc[i][j] = __builtin_amdgcn_mfma_f32_16x16x32_bf16(af[i], bfr[j], acc[i][j], 0, 0, 0);
        }
    }
}

// GEMM1: QKV = x(f32) * Wcat.
//   Q (scaled) -> qb[bh][s][d], K -> kb[bh][s][d]  (both via LDS roundtrip, b128 out)
//   V -> LDS-transpose -> vt[bh][d][s] (b128 out)
__global__ __launch_bounds__(256) void gemm_qkv(const float* __restrict__ x,
                                                const unsigned short* __restrict__ wcat,
                                                unsigned short* __restrict__ qb,
                                                unsigned short* __restrict__ kb,
                                                unsigned short* __restrict__ vt) {
    __shared__ unsigned short Smem[2 * 128 * LDSW];   // 36864B; Tb needs 34816B
    unsigned short* As = Smem;
    unsigned short* Bs = Smem + 128 * LDSW;
    f32x4 acc[4][4];
    int m0 = blockIdx.x * 128, n0 = blockIdx.y * 128;
    gemm_tile_core<1, 0>(x, wcat, EMB, m0, n0, As, Bs, acc);

    int t = threadIdx.x, wave = t >> 6, lane = t & 63;
    int wm = (wave >> 1) * 64, wn = (wave & 1) * 64, lr = lane & 15, quad = lane >> 4;
    int b  = m0 >> 11;
    int s0 = m0 & 2047;
    unsigned short* Tb = Smem;                 // reuse: [128][136]

    if (n0 < 2048) {
        bool isQ = (n0 < 1024);
        unsigned short* dst = isQ ? qb : kb;
        float sc = isQ ? QSCALE : 1.0f;
        __syncthreads();                       // done reading As/Bs
        #pragma unroll
        for (int i = 0; i < 4; i++)
            #pragma unroll
            for (int j = 0; j < 4; j++)
                #pragma unroll
                for (int e = 0; e < 4; e++)
                    Tb[(wm + i * 16 + quad * 4 + e) * 136 + wn + j * 16 + lr] = f2bf(acc[i][j][e] * sc);
        __syncthreads();
        #pragma unroll
        for (int p = 0; p < 8; p++) {
            int r  = p * 16 + (t >> 4);
            int ch = (t & 15) * 8;
            int n  = n0 + ch;
            int h  = (n >> 6) & 15, d = ch & 63;
            *(uint4*)(dst + (((size_t)(b * NH + h)) * S_LEN + s0 + r) * HD + d) =
                *(const uint4*)(Tb + r * 136 + ch);
        }
    } else {
        // V: transpose in LDS, then coalesced rows of vt[bh][d][s]
        __syncthreads();
        #pragma unroll
        for (int i = 0; i < 4; i++)
            #pragma unroll
            for (int j = 0; j < 4; j++)
                #pragma unroll
                for (int e = 0; e < 4; e++)
                    Tb[(wn + j * 16 + lr) * 136 + (wm + i * 16 + quad * 4 + e)] = f2bf(acc[i][j][e]);
        __syncthreads();
        #pragma unroll
        for (int p = 0; p < 8; p++) {
            int nl  = p * 16 + (t >> 4);
            int n   = n0 + nl;
            int h   = (n >> 6) & 15, d = n & 63;
            int col = (t & 15) * 8;
            *(uint4*)(vt + (((size_t)(b * NH + h)) * HD + d) * S_LEN + s0 + col) =
                *(const uint4*)(Tb + nl * 136 + col);
        }
    }
}

// GEMM2: out = ao * w_proj(f32)^T + b
__global__ __launch_bounds__(256) void gemm_proj(const unsigned short* __restrict__ ao,
                                                 const float* __restrict__ wproj,
                                                 const float* __restrict__ bproj,
                                                 float* __restrict__ out) {
    __shared__ unsigned short Smem[2 * 128 * LDSW];
    f32x4 acc[4][4];
    int m0 = blockIdx.x * 128, n0 = blockIdx.y * 128;
    gemm_tile_core<0, 1>(ao, wproj, EMB, m0, n0, Smem, Smem + 128 * LDSW, acc);

    int t = threadIdx.x, wave = t >> 6, lane = t & 63;
    int wm = (wave >> 1) * 64, wn = (wave & 1) * 64, lr = lane & 15, quad = lane >> 4;
    #pragma unroll
    for (int i = 0; i < 4; i++)
        #pragma unroll
        for (int j = 0; j < 4; j++) {
            int n = n0 + wn + j * 16 + lr;
            float bias = bproj[n];
            #pragma unroll
            for (int e = 0; e < 4; e++) {
                int m = m0 + wm + i * 16 + quad * 4 + e;
                out[(size_t)m * EMB + n] = acc[i][j][e] + bias;
            }
        }
}

// ---------------- MFMA flash attention, causal, S^T-swapped ----------------
// 512 blocks x 256 threads = 32 bh x 16 chunks of 128 rows; 4 waves x 32 rows.
// Each wave owns TWO 16-row q-groups: one Kf/Vf LDS read feeds two MFMAs
// (K/V fragment-read traffic per q-row halved vs 8-wave x 16-row).
// Heavy-first chunk order: CU hosts blocks c & c+256 = chunks {15-g, g} ->
// constant 34 tiles per CU. Double-buffered K/V LDS: ONE barrier per tile.
// Softmax: exp2(S) raw (constant exponent bias cancels in O/l); l via
// MFMA-vs-ones; P->bf16 via v_cvt_pk_bf16_f32.
__global__ __launch_bounds__(256) void attn_mfma(const unsigned short* __restrict__ qb,
                                                 const unsigned short* __restrict__ kb,
                                                 const unsigned short* __restrict__ vtb,
                                                 unsigned short* __restrict__ ao) {
    __shared__ unsigned short Ks[2][64 * LDSW];     // [buf][key][d]
    __shared__ unsigned short Vs[2][64 * LDSW];     // [buf][d][key]
    __shared__ unsigned short Ps[128 * LDSW];       // 4 waves x 32 rows [q][key]; reused as O buffer

    int bIdx = blockIdx.x;
    int bh   = bIdx & 31;
    int grp  = bIdx >> 5;
    int chunk = (grp < 8) ? (15 - grp) : (grp - 8);   // heavy chunks first
    int b = bh >> 4, h = bh & 15;
    int t = threadIdx.x, wave = t >> 6, lane = t & 63;
    int c = lane & 15, quad = lane >> 4;

    const unsigned short* Q  = qb  + (size_t)bh * S_LEN * HD;
    const unsigned short* K  = kb  + (size_t)bh * S_LEN * HD;
    const unsigned short* Vt = vtb + (size_t)bh * HD * S_LEN;

    int r0 = chunk * 128;
    int rw = r0 + wave * 32;                 // wave's 32 q rows (groups at +0, +16)

    // Q frags (B-operand): B[n=q=c][k=d], per group
    bf16x8 Qf[2][2];
    #pragma unroll
    for (int g = 0; g < 2; g++)
        #pragma unroll
        for (int ks = 0; ks < 2; ks++)
            Qf[g][ks] = *(const bf16x8*)(Q + (size_t)(rw + g * 16 + c) * HD + ks * 32 + quad * 8);

    f32x4 O[2][4];
    f32x4 lacc[2];
    #pragma unroll
    for (int g = 0; g < 2; g++) {
        lacc[g] = (f32x4)(0.0f);
        #pragma unroll
        for (int dt = 0; dt < 4; dt++) O[g][dt] = (f32x4)(0.0f);
    }

    const short oneb = (short)0x3F80;
    bf16x8 ones = {oneb, oneb, oneb, oneb, oneb, oneb, oneb, oneb};

    unsigned short* Pw = Ps + wave * 32 * LDSW;
    int sr = t >> 3, scg = (t & 7) * 8;      // 256 thr: sr 0..31, two rows each

    int NT = (r0 + 128) >> 6;                // tiles this block computes (>= 2)

    // prologue: stage tile 0 directly, load tile 1 into regs
    uint4 kpre0 = *(const uint4*)(K  + (size_t)sr * HD + scg);
    uint4 kpre1 = *(const uint4*)(K  + (size_t)(sr + 32) * HD + scg);
    uint4 vpre0 = *(const uint4*)(Vt + (size_t)sr * S_LEN + scg);
    uint4 vpre1 = *(const uint4*)(Vt + (size_t)(sr + 32) * S_LEN + scg);
    *(uint4*)(Ks[0] + sr * LDSW + scg)        = kpre0;
    *(uint4*)(Ks[0] + (sr + 32) * LDSW + scg) = kpre1;
    *(uint4*)(Vs[0] + sr * LDSW + scg)        = vpre0;
    *(uint4*)(Vs[0] + (sr + 32) * LDSW + scg) = vpre1;
    kpre0 = *(const uint4*)(K  + (size_t)(64 + sr) * HD + scg);
    kpre1 = *(const uint4*)(K  + (size_t)(96 + sr) * HD + scg);
    vpre0 = *(const uint4*)(Vt + (size_t)sr * S_LEN + 64 + scg);
    vpre1 = *(const uint4*)(Vt + (size_t)(sr + 32) * S_LEN + 64 + scg);

    for (int tt = 0; tt < NT; ++tt) {
        __syncthreads();   // tile tt visible; tile tt-1 readers done
        if (tt + 1 < NT) {
            unsigned short* Kd = Ks[(tt + 1) & 1];
            unsigned short* Vd = Vs[(tt + 1) & 1];
            *(uint4*)(Kd + sr * LDSW + scg)        = kpre0;
            *(uint4*)(Kd + (sr + 32) * LDSW + scg) = kpre1;
            *(uint4*)(Vd + sr * LDSW + scg)        = vpre0;
            *(uint4*)(Vd + (sr + 32) * LDSW + scg) = vpre1;
            if (tt + 2 < NT) {
                kpre0 = *(const uint4*)(K  + (size_t)((tt + 2) * 64 + sr) * HD + scg);
                kpre1 = *(const uint4*)(K  + (size_t)((tt + 2) * 64 + 32 + sr) * HD + scg);
                vpre0 = *(const uint4*)(Vt + (size_t)sr * S_LEN + (tt + 2) * 64 + scg);
                vpre1 = *(const uint4*)(Vt + (size_t)(sr + 32) * S_LEN + (tt + 2) * 64 + scg);
            }
        }
        int j0 = tt << 6;
        if (j0 <= rw + 31) {
            const unsigned short* Kc = Ks[tt & 1];
            const unsigned short* Vc = Vs[tt & 1];

            // S^T = K Q^T : D[m=key][n=q]; Kf shared across both q-groups
            f32x4 S4[2][4];
            #pragma unroll
            for (int g = 0; g < 2; g++)
                #pragma unroll
                for (int kt = 0; kt < 4; kt++) S4[g][kt] = (f32x4)(0.0f);
            __builtin_amdgcn_s_setprio(1);
            #pragma unroll
            for (int ks = 0; ks < 2; ks++) {
                bf16x8 Kf[4];
                #pragma unroll
                for (int kt = 0; kt < 4; kt++)
                    Kf[kt] = *(const bf16x8*)(Kc + (kt * 16 + c) * LDSW + ks * 32 + quad * 8);
                #pragma unroll
                for (int kt = 0; kt < 4; kt++)
                    S4[0][kt] = __builtin_amdgcn_mfma_f32_16x16x32_bf16(Kf[kt], Qf[0][ks], S4[0][kt], 0, 0, 0);
                #pragma unroll
                for (int kt = 0; kt < 4; kt++)
                    S4[1][kt] = __builtin_amdgcn_mfma_f32_16x16x32_bf16(Kf[kt], Qf[1][ks], S4[1][kt], 0, 0, 0);
            }
            __builtin_amdgcn_s_setprio(0);

            #pragma unroll
            for (int g = 0; g < 2; g++) {
                bool need_mask = (j0 + 63 > rw + g * 16);
                #pragma unroll
                for (int kt = 0; kt < 4; kt++) {
                    float p0 = EXP2(S4[g][kt][0]);
                    float p1 = EXP2(S4[g][kt][1]);
                    float p2 = EXP2(S4[g][kt][2]);
                    float p3 = EXP2(S4[g][kt][3]);
                    if (need_mask) {
                        int key  = j0 + kt * 16 + quad * 4;
                        int qrow = rw + g * 16 + c;
                        if (key + 0 > qrow) p0 = 0.0f;
                        if (key + 1 > qrow) p1 = 0.0f;
                        if (key + 2 > qrow) p2 = 0.0f;
                        if (key + 3 > qrow) p3 = 0.0f;
                    }
                    uint2 pk;
                    pk.x = cvtpk(p0, p1);
                    pk.y = cvtpk(p2, p3);
                    *(uint2*)(Pw + (g * 16 + c) * LDSW + kt * 16 + quad * 4) = pk;
                }
            }

            // O += P V ; l += P * ones  (Af per group, Vf shared)
            __builtin_amdgcn_s_setprio(1);
            #pragma unroll
            for (int ks = 0; ks < 2; ks++) {
                bf16x8 Af0 = *(const bf16x8*)(Pw + c * LDSW + ks * 32 + quad * 8);
                bf16x8 Af1 = *(const bf16x8*)(Pw + (16 + c) * LDSW + ks * 32 + quad * 8);
                lacc[0] = __builtin_amdgcn_mfma_f32_16x16x32_bf16(Af0, ones, lacc[0], 0, 0, 0);
                lacc[1] = __builtin_amdgcn_mfma_f32_16x16x32_bf16(Af1, ones, lacc[1], 0, 0, 0);
                #pragma unroll
                for (int dt = 0; dt < 4; dt++) {
                    bf16x8 Vf = *(const bf16x8*)(Vc + (dt * 16 + c) * LDSW + ks * 32 + quad * 8);
                    O[0][dt] = __builtin_amdgcn_mfma_f32_16x16x32_bf16(Af0, Vf, O[0][dt], 0, 0, 0);
                    O[1][dt] = __builtin_amdgcn_mfma_f32_16x16x32_bf16(Af1, Vf, O[1][dt], 0, 0, 0);
                }
            }
            __builtin_amdgcn_s_setprio(0);
        }
    }

    // normalize: l lands in C-layout rows (quad*4+e) == O's rows; no cross-lane needed
    float inv[2][4];
    #pragma unroll
    for (int g = 0; g < 2; g++)
        #pragma unroll
        for (int e = 0; e < 4; e++) inv[g][e] = 1.0f / lacc[g][e];

    // O -> wave-private LDS region (aliases Pw) -> coalesced b128 global
    #pragma unroll
    for (int g = 0; g < 2; g++)
        #pragma unroll
        for (int dt = 0; dt < 4; dt++)
            #pragma unroll
            for (int e = 0; e < 4; e++)
                Ps[(wave * 32 + g * 16 + quad * 4 + e) * LDSW + dt * 16 + c] = f2bf(O[g][dt][e] * inv[g][e]);
    __syncthreads();
    #pragma unroll
    for (int p = 0; p < 4; p++) {
        int r = p * 32 + sr;
        *(uint4*)(ao + ((size_t)(b * S_LEN + r0 + r)) * EMB + h * HD + scg) =
            *(const uint4*)(Ps + r * LDSW + scg);
    }
}

// ---------------- launch ----------------
extern "C" void kernel_launch(void* const* d_in, const int* in_sizes, int n_in,
                              void* d_out, int out_size, void* d_ws, size_t ws_size,
                              hipStream_t stream) {
    const float* x     = (const float*)d_in[0];
    const float* wq    = (const float*)d_in[1];
    const float* wk    = (const float*)d_in[2];
    const float* wv    = (const float*)d_in[3];
    const float* wproj = (const float*)d_in[4];
    const float* bproj = (const float*)d_in[5];
    float* out = (float*)d_out;

    char* ws = (char*)d_ws;
    unsigned short* wcat = (unsigned short*)(ws + 0);          //  6 MB  [3072,1024] (B^T)
    unsigned short* qb   = (unsigned short*)(ws + 8388608);    //  8 MB  [B,H,S,D] (x QSCALE)
    unsigned short* kb   = (unsigned short*)(ws + 16777216);   //  8 MB  [B,H,S,D]
    unsigned short* vt   = (unsigned short*)(ws + 25165824);   //  8 MB  [B,H,D,S]
    unsigned short* ao   = (unsigned short*)(ws + 33554432);   //  8 MB  [4096,1024]

    prep_wcat<<<384, 256, 0, stream>>>(wq, wk, wv, wcat);
    gemm_qkv<<<dim3(32, 24), 256, 0, stream>>>(x, wcat, qb, kb, vt);
    attn_mfma<<<512, 256, 0, stream>>>(qb, kb, vt, ao);
    gemm_proj<<<dim3(32, 8), 256, 0, stream>>>(ao, wproj, bproj, out);
}